// Round 8
// baseline (23.703 us; speedup 1.0000x reference)
//
#include <hip/hip_runtime.h>

// out[b][s][d] = W[d][s] + bias[d], b<4, s<4096, d<1024
// W: [1024][8192] fp32 row-major; out: [4][4096][1024] fp32.
//
// R8 discriminator: two kernels.
//  A) transpose W(+bias) -> out[0] only   (17 MB strided read + 17 MB dense write)
//  B) broadcast out[0] -> out[1..3]       (17 MB read, L3-resident + 50 MB dense write,
//                                          fill-kernel-like: no LDS, no barriers)
// If strided-read/write interference was the limiter: ~15 us.
// If fixed per-launch overhead dominates: ~22+ us -> R3 was roofline.
// History: NT -19% (R2); occupancy neutral (R3); read amp +59% (R4);
// write-frag neutral (R5); pipelining neutral (R6); read-seg neutral (R7).

constexpr int S = 4096;
constexpr int D = 1024;
constexpr int MAXLEN = 8192;
constexpr int TS = 32;            // s-rows per tile
constexpr int TD = 64;            // d-cols per tile
constexpr int PAD = 1;
constexpr int NTS = S / TS;       // 128
constexpr int NTD = D / TD;       // 16

__global__ __launch_bounds__(256)
void pos_emb_transpose_kernel(const float* __restrict__ W,
                              const float* __restrict__ bias,
                              float* __restrict__ out)   // batch 0 slab
{
    __shared__ float tile[TD][TS + PAD];

    const int ts = blockIdx.x % NTS;
    const int td = blockIdx.x / NTS;
    const int s0 = ts * TS;
    const int d0 = td * TD;
    const int tid = threadIdx.x;

    // Load: lanes along s, 128 B per W row, 2 passes of 32 rows.
    {
        const int c  = tid & 7;
        const int r  = tid >> 3;
        #pragma unroll
        for (int i = 0; i < 2; ++i) {
            const int dl = r + i * 32;
            const float4 v = *reinterpret_cast<const float4*>(
                &W[(size_t)(d0 + dl) * MAXLEN + s0 + c * 4]);
            tile[dl][c * 4 + 0] = v.x;
            tile[dl][c * 4 + 1] = v.y;
            tile[dl][c * 4 + 2] = v.z;
            tile[dl][c * 4 + 3] = v.w;
        }
    }
    __syncthreads();

    // Store: lanes along d, batch 0 only.
    {
        const int cd = tid & 15;
        const int rs = tid >> 4;
        const float4 bv = *reinterpret_cast<const float4*>(&bias[d0 + cd * 4]);
        #pragma unroll
        for (int i = 0; i < 2; ++i) {
            const int sl = rs + i * 16;
            float4 v;
            v.x = tile[cd * 4 + 0][sl] + bv.x;
            v.y = tile[cd * 4 + 1][sl] + bv.y;
            v.z = tile[cd * 4 + 2][sl] + bv.z;
            v.w = tile[cd * 4 + 3][sl] + bv.w;
            *reinterpret_cast<float4*>(&out[(size_t)(s0 + sl) * D + d0 + cd * 4]) = v;
        }
    }
}

// Broadcast out[0] -> out[1..3]: dense, fill-like.
__global__ __launch_bounds__(256)
void pos_emb_bcast_kernel(float* __restrict__ out)
{
    constexpr size_t N4 = (size_t)S * D / 4;     // 1,048,576 float4 per batch
    const size_t i = (size_t)blockIdx.x * blockDim.x + threadIdx.x;
    const float4* src = reinterpret_cast<const float4*>(out);
    const float4 v = src[i];
    float4* dst = reinterpret_cast<float4*>(out);
    dst[i + 1 * N4] = v;
    dst[i + 2 * N4] = v;
    dst[i + 3 * N4] = v;
}

extern "C" void kernel_launch(void* const* d_in, const int* in_sizes, int n_in,
                              void* d_out, int out_size, void* d_ws, size_t ws_size,
                              hipStream_t stream) {
    // setup_inputs order: x (unused), W, b
    const float* W    = (const float*)d_in[1];
    const float* bias = (const float*)d_in[2];
    float* out        = (float*)d_out;

    const int gridA = NTS * NTD;                       // 2048 blocks
    pos_emb_transpose_kernel<<<gridA, 256, 0, stream>>>(W, bias, out);

    const int gridB = (int)((size_t)S * D / 4 / 256);  // 4096 blocks
    pos_emb_bcast_kernel<<<gridB, 256, 0, stream>>>(out);
}

// Round 9
// 17.797 us; speedup vs baseline: 1.3318x; 1.3318x over previous
//
#include <hip/hip_runtime.h>

// out[b][s][d] = W[d][s] + bias[d], b<4, s<4096, d<1024
// W: [1024][8192] fp32 row-major; out: [4][4096][1024] fp32.
//
// ROOFLINE config (R3 revert). LDS 64x32 (+1 pad) transpose tile;
// coalesced float4 both sides; batch replication in-register.
// Exec time ~12.2 us = 84 MB @ ~6.9 TB/s (copy-class floor); the
// remaining ~5.7 us of dur_us is fixed per-dispatch/replay overhead,
// proven by the R8 two-kernel discriminator (+5.75 us for one extra
// dispatch at equal traffic).
// Ledger: NT -19% (R2); occupancy 4<->8 blk/CU neutral (R3); batch-in-
// grid read amp +59% (R4); 1KB write frags neutral (R5); reg-pipelining
// neutral (R6); 512B read segs neutral (R7); 2-kernel split +32% (R8).

constexpr int S = 4096;
constexpr int D = 1024;
constexpr int MAXLEN = 8192;
constexpr int BATCH = 4;
constexpr int TS = 32;   // tile extent along s
constexpr int TD = 64;   // tile extent along d
constexpr int PAD = 1;   // LDS row stride 33 floats -> 2 lanes/bank (free)

__global__ __launch_bounds__(256)
void pos_emb_kernel(const float* __restrict__ W,
                    const float* __restrict__ bias,
                    float* __restrict__ out)
{
    __shared__ float tile[TD][TS + PAD];

    constexpr int nTileS = S / TS;             // 128
    const int ts = blockIdx.x % nTileS;
    const int td = blockIdx.x / nTileS;
    const int s0 = ts * TS;
    const int d0 = td * TD;
    const int tid = threadIdx.x;

    // ---- Load phase: lanes along s (coalesced float4 from W rows) ----
    {
        const int c4 = tid & 7;    // which float4 within the s-row (8 per row)
        const int r  = tid >> 3;   // d-row base (0..31), 2 passes of 32 rows
        #pragma unroll
        for (int i = 0; i < 2; ++i) {
            const int dl = r + i * 32;
            const float4 v = *reinterpret_cast<const float4*>(
                &W[(size_t)(d0 + dl) * MAXLEN + s0 + c4 * 4]);
            tile[dl][c4 * 4 + 0] = v.x;
            tile[dl][c4 * 4 + 1] = v.y;
            tile[dl][c4 * 4 + 2] = v.z;
            tile[dl][c4 * 4 + 3] = v.w;
        }
    }
    __syncthreads();

    // ---- Store phase: lanes along d (coalesced float4 to out rows) ----
    {
        const int cd = tid & 15;   // which float4 along d (16 per row)
        const int rs = tid >> 4;   // s-row base (0..15), 2 passes of 16 rows
        const float4 bv = *reinterpret_cast<const float4*>(&bias[d0 + cd * 4]);
        #pragma unroll
        for (int i = 0; i < 2; ++i) {
            const int sl = rs + i * 16;
            float4 v;
            v.x = tile[cd * 4 + 0][sl] + bv.x;
            v.y = tile[cd * 4 + 1][sl] + bv.y;
            v.z = tile[cd * 4 + 2][sl] + bv.z;
            v.w = tile[cd * 4 + 3][sl] + bv.w;
            const size_t base = (size_t)(s0 + sl) * D + d0 + cd * 4;
            #pragma unroll
            for (int b = 0; b < BATCH; ++b) {
                *reinterpret_cast<float4*>(&out[base + (size_t)b * S * D]) = v;
            }
        }
    }
}

extern "C" void kernel_launch(void* const* d_in, const int* in_sizes, int n_in,
                              void* d_out, int out_size, void* d_ws, size_t ws_size,
                              hipStream_t stream) {
    // setup_inputs order: x (unused), W, b
    const float* W    = (const float*)d_in[1];
    const float* bias = (const float*)d_in[2];
    float* out        = (float*)d_out;

    const int grid = (S / TS) * (D / TD);   // 2048 blocks, 256 threads
    pos_emb_kernel<<<grid, 256, 0, stream>>>(W, bias, out);
}